// Round 10
// baseline (96.538 us; speedup 1.0000x reference)
//
#include <hip/hip_runtime.h>

#define NG 20000
#define NB 1024

typedef float v4f __attribute__((ext_vector_type(4)));

constexpr int THREADS = 256;            // 4 waves
constexpr int GENES_PER_BLOCK = 512;    // 128 gene-lanes * 4 genes
constexpr int NGB = 40;                 // ceil(20000/512)
constexpr int BB  = 32;                 // batches per block
constexpr int NBB = NB / BB;            // 32
constexpr int GB_PER_XCD = NGB / 8;     // 5 gene-chunks per XCD

// R9 (best: 45.2us) with ONE change: launch_bounds(256,5) -> 5 blocks/CU
// -> all 1280 blocks resident in a single pass (was 4/CU + a sequential
// 5th generation per CU). VGPR cap drops 128->102; kernel needs ~95-100.
// Gating check: if this forces a spill/rematerialization (R4 mode), dur
// blows up -> revert to (256,4) and declare roofline.
__global__ __launch_bounds__(THREADS, 5)
void cgm_kernel(const float* __restrict__ x,
                const float* __restrict__ w1,
                const float* __restrict__ b1,
                const float* __restrict__ w2,
                const float* __restrict__ b2,
                const float* __restrict__ wg,
                const float* __restrict__ bg,
                float* __restrict__ out)
{
    // XCD mapping: each XCD owns 5 gene-chunks x 32 batch-chunks.
    const int bid = (int)blockIdx.x;          // 0..1279
    const int xcd = bid & 7;
    const int j   = bid >> 3;                 // 0..159
    const int gb  = xcd * GB_PER_XCD + (j / NBB);   // 0..39
    const int bb  = j % NBB;                  // 0..31

    const int lane = (int)threadIdx.x & 63;
    const int wv   = (int)threadIdx.x >> 6;
    const int t    = lane >> 5;               // tech 0/1 per half-wave
    const int gl   = wv * 32 + (lane & 31);   // gene-lane 0..127
    const int gbase = gb * GENES_PER_BLOCK + gl * 4;
    if (gbase >= NG) return;                  // tail (gb==39): partners stay paired

    // ---- per-thread params in registers (own tech only) ----
    v4f W1[4], B1[4], W2[4];
    float B2v[4];
    const size_t r0 = (size_t)t * NG + (size_t)gbase;
    #pragma unroll
    for (int g = 0; g < 4; ++g) {
        W1[g]  = *(const v4f*)(w1 + (r0 + g) * 4);
        B1[g]  = *(const v4f*)(b1 + (r0 + g) * 4);
        W2[g]  = *(const v4f*)(w2 + (r0 + g) * 4);
        B2v[g] = b2[r0 + g];
    }
    const v4f wgA = *(const v4f*)(wg + (size_t)gbase * 2);      // g0t0 g0t1 g1t0 g1t1
    const v4f wgB = *(const v4f*)(wg + (size_t)gbase * 2 + 4);  // g2t0 g2t1 g3t0 g3t1
    const v4f bgv = *(const v4f*)(bg + gbase);

    const float* xbase = x + (size_t)t * NG + (size_t)gbase;
    float*       obase = out + (size_t)gbase;
    const int b_lo = bb * BB;

    auto load4 = [&](v4f* dst, int bi) {
        #pragma unroll
        for (int k = 0; k < 4; ++k)
            dst[k] = *(const v4f*)(xbase + (size_t)(b_lo + bi + k) * (2 * NG));  // plain load
    };
    auto proc1 = [&](v4f xv, int b_abs) {
        float s[4];
        #pragma unroll
        for (int g = 0; g < 4; ++g) {
            const float v = xv[g];
            float h, acc = 0.f;
            h = fmaxf(fmaf(v, W1[g].x, B1[g].x), 0.f); acc = fmaf(h, W2[g].x, acc);
            h = fmaxf(fmaf(v, W1[g].y, B1[g].y), 0.f); acc = fmaf(h, W2[g].y, acc);
            h = fmaxf(fmaf(v, W1[g].z, B1[g].z), 0.f); acc = fmaf(h, W2[g].z, acc);
            h = fmaxf(fmaf(v, W1[g].w, B1[g].w), 0.f); acc = fmaf(h, W2[g].w, acc);
            s[g] = fmaxf(acc + B2v[g], 0.f);
        }
        float so[4];
        #pragma unroll
        for (int g = 0; g < 4; ++g) so[g] = __shfl_xor(s[g], 32, 64);
        if (t == 0) {
            v4f o;
            o.x = fmaxf(fmaf(s[0], wgA.x, fmaf(so[0], wgA.y, bgv.x)), 0.f);
            o.y = fmaxf(fmaf(s[1], wgA.z, fmaf(so[1], wgA.w, bgv.y)), 0.f);
            o.z = fmaxf(fmaf(s[2], wgB.x, fmaf(so[2], wgB.y, bgv.z)), 0.f);
            o.w = fmaxf(fmaf(s[3], wgB.z, fmaf(so[3], wgB.w, bgv.w)), 0.f);
            *(v4f*)(obase + (size_t)b_abs * NG) = o;   // plain store
        }
    };

    v4f A[4], B[4];
    load4(A, 0);
    load4(B, 4);
    #pragma unroll
    for (int bi = 0; bi < BB; bi += 8) {
        #pragma unroll
        for (int k = 0; k < 4; ++k) proc1(A[k], b_lo + bi + k);
        if (bi + 8 < BB) load4(A, bi + 8);
        #pragma unroll
        for (int k = 0; k < 4; ++k) proc1(B[k], b_lo + bi + 4 + k);
        if (bi + 12 < BB) load4(B, bi + 12);
    }
}

extern "C" void kernel_launch(void* const* d_in, const int* in_sizes, int n_in,
                              void* d_out, int out_size, void* d_ws, size_t ws_size,
                              hipStream_t stream) {
    const float* x  = (const float*)d_in[0];
    const float* w1 = (const float*)d_in[1];
    const float* b1 = (const float*)d_in[2];
    const float* w2 = (const float*)d_in[3];
    const float* b2 = (const float*)d_in[4];
    const float* wg = (const float*)d_in[5];
    const float* bg = (const float*)d_in[6];
    float* out = (float*)d_out;

    dim3 grid(NGB * NBB);   // 40 * 32 = 1280 blocks (5/CU, fully resident)
    cgm_kernel<<<grid, THREADS, 0, stream>>>(x, w1, b1, w2, b2, wg, bg, out);
}

// Round 11
// 45.737 us; speedup vs baseline: 2.1107x; 2.1107x over previous
//
#include <hip/hip_runtime.h>

#define NG 20000
#define NB 1024

typedef float v4f __attribute__((ext_vector_type(4)));

constexpr int THREADS = 256;            // 4 waves
constexpr int GENES_PER_BLOCK = 512;    // 128 gene-lanes * 4 genes
constexpr int NGB = 40;                 // ceil(20000/512)
constexpr int BB  = 32;                 // batches per block
constexpr int NBB = NB / BB;            // 32
constexpr int GB_PER_XCD = NGB / 8;     // 5 gene-chunks per XCD

// FINAL (R9, session best: 45.2us = ~93% of the 6.29TB/s copy ceiling on
// raw traffic). Half-wave tech split (lanes 0-31 tech0 / 32-63 tech1),
// 4 genes/thread, params in registers; 8-deep batch pipeline; PLAIN loads
// and PLAIN stores (NT on either side costs 3-12%: defeats L2/MSHR
// coalescing on loads, write-combining on stores).
// launch_bounds(256,4): (256,5)->48 VGPR rematerialization, 2x slower (R10);
// (256,8)->32 VGPR, 3.3x slower (R4). Do not touch.
__global__ __launch_bounds__(THREADS, 4)
void cgm_kernel(const float* __restrict__ x,
                const float* __restrict__ w1,
                const float* __restrict__ b1,
                const float* __restrict__ w2,
                const float* __restrict__ b2,
                const float* __restrict__ wg,
                const float* __restrict__ bg,
                float* __restrict__ out)
{
    // XCD mapping: each XCD owns 5 gene-chunks x 32 batch-chunks.
    const int bid = (int)blockIdx.x;          // 0..1279
    const int xcd = bid & 7;
    const int j   = bid >> 3;                 // 0..159
    const int gb  = xcd * GB_PER_XCD + (j / NBB);   // 0..39
    const int bb  = j % NBB;                  // 0..31

    const int lane = (int)threadIdx.x & 63;
    const int wv   = (int)threadIdx.x >> 6;
    const int t    = lane >> 5;               // tech 0/1 per half-wave
    const int gl   = wv * 32 + (lane & 31);   // gene-lane 0..127
    const int gbase = gb * GENES_PER_BLOCK + gl * 4;
    if (gbase >= NG) return;                  // tail (gb==39): partners stay paired

    // ---- per-thread params in registers (own tech only) ----
    v4f W1[4], B1[4], W2[4];
    float B2v[4];
    const size_t r0 = (size_t)t * NG + (size_t)gbase;
    #pragma unroll
    for (int g = 0; g < 4; ++g) {
        W1[g]  = *(const v4f*)(w1 + (r0 + g) * 4);
        B1[g]  = *(const v4f*)(b1 + (r0 + g) * 4);
        W2[g]  = *(const v4f*)(w2 + (r0 + g) * 4);
        B2v[g] = b2[r0 + g];
    }
    const v4f wgA = *(const v4f*)(wg + (size_t)gbase * 2);      // g0t0 g0t1 g1t0 g1t1
    const v4f wgB = *(const v4f*)(wg + (size_t)gbase * 2 + 4);  // g2t0 g2t1 g3t0 g3t1
    const v4f bgv = *(const v4f*)(bg + gbase);

    const float* xbase = x + (size_t)t * NG + (size_t)gbase;
    float*       obase = out + (size_t)gbase;
    const int b_lo = bb * BB;

    auto load4 = [&](v4f* dst, int bi) {
        #pragma unroll
        for (int k = 0; k < 4; ++k)
            dst[k] = *(const v4f*)(xbase + (size_t)(b_lo + bi + k) * (2 * NG));  // plain load
    };
    auto proc1 = [&](v4f xv, int b_abs) {
        float s[4];
        #pragma unroll
        for (int g = 0; g < 4; ++g) {
            const float v = xv[g];
            float h, acc = 0.f;
            h = fmaxf(fmaf(v, W1[g].x, B1[g].x), 0.f); acc = fmaf(h, W2[g].x, acc);
            h = fmaxf(fmaf(v, W1[g].y, B1[g].y), 0.f); acc = fmaf(h, W2[g].y, acc);
            h = fmaxf(fmaf(v, W1[g].z, B1[g].z), 0.f); acc = fmaf(h, W2[g].z, acc);
            h = fmaxf(fmaf(v, W1[g].w, B1[g].w), 0.f); acc = fmaf(h, W2[g].w, acc);
            s[g] = fmaxf(acc + B2v[g], 0.f);
        }
        float so[4];
        #pragma unroll
        for (int g = 0; g < 4; ++g) so[g] = __shfl_xor(s[g], 32, 64);
        if (t == 0) {
            v4f o;
            o.x = fmaxf(fmaf(s[0], wgA.x, fmaf(so[0], wgA.y, bgv.x)), 0.f);
            o.y = fmaxf(fmaf(s[1], wgA.z, fmaf(so[1], wgA.w, bgv.y)), 0.f);
            o.z = fmaxf(fmaf(s[2], wgB.x, fmaf(so[2], wgB.y, bgv.z)), 0.f);
            o.w = fmaxf(fmaf(s[3], wgB.z, fmaf(so[3], wgB.w, bgv.w)), 0.f);
            *(v4f*)(obase + (size_t)b_abs * NG) = o;   // plain store
        }
    };

    v4f A[4], B[4];
    load4(A, 0);
    load4(B, 4);
    #pragma unroll
    for (int bi = 0; bi < BB; bi += 8) {
        #pragma unroll
        for (int k = 0; k < 4; ++k) proc1(A[k], b_lo + bi + k);
        if (bi + 8 < BB) load4(A, bi + 8);
        #pragma unroll
        for (int k = 0; k < 4; ++k) proc1(B[k], b_lo + bi + 4 + k);
        if (bi + 12 < BB) load4(B, bi + 12);
    }
}

extern "C" void kernel_launch(void* const* d_in, const int* in_sizes, int n_in,
                              void* d_out, int out_size, void* d_ws, size_t ws_size,
                              hipStream_t stream) {
    const float* x  = (const float*)d_in[0];
    const float* w1 = (const float*)d_in[1];
    const float* b1 = (const float*)d_in[2];
    const float* w2 = (const float*)d_in[3];
    const float* b2 = (const float*)d_in[4];
    const float* wg = (const float*)d_in[5];
    const float* bg = (const float*)d_in[6];
    float* out = (float*)d_out;

    dim3 grid(NGB * NBB);   // 40 * 32 = 1280 blocks
    cgm_kernel<<<grid, THREADS, 0, stream>>>(x, w1, b1, w2, b2, wg, bg, out);
}